// Round 4
// baseline (291.783 us; speedup 1.0000x reference)
//
#include <hip/hip_runtime.h>

// StepConditionalLoReFT: out = h + Rn^T (W h + b - Rn h) per step s.
// FP32 tensors. B=8 S=50 T=77 D=1024 r=16.
//
// prep_kernel: Rn = R/max(||R||,eps), M = W - Rn -> ws as bf16
//              (M[s][r][d] row-major, RnT[s][d][r]). One wave per (s,r).
// loreft_fast: block = 16 tokens, 4 waves. grid (50, 39) = 1950 blocks.
//   Phase 1 (split-K): wave w does K in [w*256, w*256+256): 8x mfma 16x16x32
//            partial c -> LDS, reduce + bias -> cbuf (bf16)
//   Phase 2 (split-D): wave w does d in [w*256, w*256+256): 16x mfma
//            out^T = Rn^T c^T + h^T  (h enters as MFMA C operand)

typedef __attribute__((ext_vector_type(8))) short short8;
typedef __attribute__((ext_vector_type(4))) float floatx4;

__device__ __forceinline__ short f2bf(float f) {
  unsigned u = __float_as_uint(f);
  u += 0x7fffu + ((u >> 16) & 1u);   // round-to-nearest-even
  return (short)(u >> 16);
}

#define S_ 50
#define T_ 77
#define NTOK 616   // B*T tokens per step s

// ---------------------------------------------------------------------------
// prep: one wave per (s,r) row. 800 waves -> 200 blocks x 256.
// ---------------------------------------------------------------------------
__global__ __launch_bounds__(256) void prep_kernel(
    const float* __restrict__ RG, const float* __restrict__ WG,
    short* __restrict__ Mbf, short* __restrict__ RtT) {
  const int wid = blockIdx.x * 4 + (threadIdx.x >> 6);   // 0..799 = s*16+r
  const int lane = threadIdx.x & 63;
  const int s = wid >> 4, r = wid & 15;

  const floatx4* Rrow = (const floatx4*)(RG + ((size_t)wid << 10));
  const floatx4* Wrow = (const floatx4*)(WG + ((size_t)wid << 10));
  floatx4 rv0 = Rrow[lane * 4 + 0];
  floatx4 rv1 = Rrow[lane * 4 + 1];
  floatx4 rv2 = Rrow[lane * 4 + 2];
  floatx4 rv3 = Rrow[lane * 4 + 3];
  float ss = 0.f;
#pragma unroll
  for (int j = 0; j < 4; ++j)
    ss += rv0[j] * rv0[j] + rv1[j] * rv1[j] + rv2[j] * rv2[j] + rv3[j] * rv3[j];
#pragma unroll
  for (int m = 1; m < 64; m <<= 1) ss += __shfl_xor(ss, m);
  const float inv = 1.0f / fmaxf(sqrtf(ss), 1e-12f);

  floatx4 wa0 = Wrow[lane * 4 + 0];
  floatx4 wa1 = Wrow[lane * 4 + 1];
  floatx4 wa2 = Wrow[lane * 4 + 2];
  floatx4 wa3 = Wrow[lane * 4 + 3];
  float rn[16];
  short8 m0, m1;
#pragma unroll
  for (int j = 0; j < 4; ++j) {
    rn[j]      = rv0[j] * inv;  m0[j]     = f2bf(wa0[j] - rn[j]);
    rn[4 + j]  = rv1[j] * inv;  m0[4 + j] = f2bf(wa1[j] - rn[4 + j]);
    rn[8 + j]  = rv2[j] * inv;  m1[j]     = f2bf(wa2[j] - rn[8 + j]);
    rn[12 + j] = rv3[j] * inv;  m1[4 + j] = f2bf(wa3[j] - rn[12 + j]);
  }
  short* mrow = Mbf + ((size_t)wid << 10);
  *(short8*)(mrow + lane * 16) = m0;
  *(short8*)(mrow + lane * 16 + 8) = m1;
  short* rt = RtT + ((size_t)s << 14);
#pragma unroll
  for (int jj = 0; jj < 16; ++jj)
    rt[((lane * 16 + jj) << 4) + r] = f2bf(rn[jj]);
}

// ---------------------------------------------------------------------------
// main: grid (50, 39) x 256 threads, 4 waves. Block = 16 tokens.
// ---------------------------------------------------------------------------
__global__ __launch_bounds__(256, 4) void loreft_fast(
    const float* __restrict__ hG, const float* __restrict__ bG,
    const short* __restrict__ Mbf, const short* __restrict__ RtT,
    float* __restrict__ outG) {
  __shared__ float redbuf[4 * 256];   // [wave][tok][r] partial c
  __shared__ short cbuf[256];         // c[tok][r] bf16, bias added

  const int s = blockIdx.x;
  const int tid = threadIdx.x;
  const int lane = tid & 63;
  const int wvi = tid >> 6;
  const int m16 = lane & 15;
  const int quad = lane >> 4;

  const int tokbase = blockIdx.y * 16;
  int tokA = tokbase + m16; if (tokA > NTOK - 1) tokA = NTOK - 1;
  const int bb = tokA / T_;
  const int tt = tokA - bb * T_;
  const size_t rowoff = ((size_t)((bb * S_ + s) * T_ + tt)) << 10;
  const floatx4* hrow4 = (const floatx4*)(hG + rowoff);

  // ===== Phase 1: split-K GEMM1, K-chunk = [wvi*256, +256) =====
  const int wofs = wvi * 256;
  const short* mrow = Mbf + ((size_t)(s * 16 + m16) << 10) + wofs;
  const floatx4* hk = hrow4 + (wofs >> 2);

  floatx4 acc = {0.f, 0.f, 0.f, 0.f};
#pragma unroll
  for (int kb = 0; kb < 8; ++kb) {
    floatx4 p0 = hk[kb * 8 + quad * 2];
    floatx4 p1 = hk[kb * 8 + quad * 2 + 1];
    short8 bfr = *(const short8*)(mrow + kb * 32 + quad * 8);
    short8 af;
#pragma unroll
    for (int j = 0; j < 4; ++j) { af[j] = f2bf(p0[j]); af[4 + j] = f2bf(p1[j]); }
    acc = __builtin_amdgcn_mfma_f32_16x16x32_bf16(af, bfr, acc, 0, 0, 0);
  }
  // partial c: lane holds c[tok=quad*4+i][r=m16]
  {
    float* rb = redbuf + wvi * 256;
#pragma unroll
    for (int i = 0; i < 4; ++i)
      rb[(quad * 4 + i) * 16 + m16] = acc[i];
  }
  __syncthreads();
  // reduce across waves + bias, pack bf16
  {
    const int tok = tid >> 4, r = tid & 15;
    const int o = tok * 16 + r;
    float c = redbuf[o] + redbuf[256 + o] + redbuf[512 + o] + redbuf[768 + o]
            + bG[s * 16 + r];
    cbuf[o] = f2bf(c);
  }
  __syncthreads();

  // ===== Phase 2: split-D GEMM2-T, d-range = [wvi*256, +256) =====
  // B-frag: B[k=r=quad*8+j][n=tok=m16] = c[tok][r]; k>=16 padded with zeros
  const short8 zero8 = {0, 0, 0, 0, 0, 0, 0, 0};
  short8 bfrag = (quad < 2) ? *(const short8*)(cbuf + m16 * 16 + quad * 8)
                            : zero8;

  const short* rt = RtT + ((size_t)s << 14);
  floatx4* orow4 = (floatx4*)(outG + rowoff);
  const bool valE = (tokbase + m16) < NTOK;
  const int q8 = (quad & 1) << 3;

#pragma unroll
  for (int u = 0; u < 16; ++u) {
    const int dt = wvi * 16 + u;
    // A-frag: Rn[r=quad*8+j][d=dt*16+m16]  (k>=16 killed by zeroed B)
    short8 ar = *(const short8*)(rt + ((dt * 16 + m16) << 4) + q8);
    // C-frag: h[tok=m16][d=dt*16+quad*4+i]
    floatx4 hv = hrow4[dt * 4 + quad];
    floatx4 o = __builtin_amdgcn_mfma_f32_16x16x32_bf16(ar, bfrag, hv, 0, 0, 0);
    if (valE) orow4[dt * 4 + quad] = o;
  }
}

extern "C" void kernel_launch(void* const* d_in, const int* in_sizes, int n_in,
                              void* d_out, int out_size, void* d_ws, size_t ws_size,
                              hipStream_t stream) {
  const float* h = (const float*)d_in[0];
  const float* R = (const float*)d_in[1];
  const float* W = (const float*)d_in[2];
  const float* b = (const float*)d_in[3];
  short* Mbf = (short*)d_ws;                      // 50*16*1024 bf16
  short* RtT = Mbf + (size_t)50 * 16 * 1024;      // 50*1024*16 bf16
  prep_kernel<<<200, 256, 0, stream>>>(R, W, Mbf, RtT);
  dim3 grid(S_, 39);
  loreft_fast<<<grid, 256, 0, stream>>>(h, b, Mbf, RtT, (float*)d_out);
}